// Round 3
// baseline (84.226 us; speedup 1.0000x reference)
//
#include <hip/hip_runtime.h>
#include <cstddef>

// Problem constants (match reference)
constexpr int H_ = 320;
constexpr int W_ = 320;
constexpr int HW_ = H_ * W_;            // 102400
constexpr int NK = 440;                 // offsets excluding center
constexpr int TS = 32;                  // spatial tile edge
constexpr int TPR = W_ / TS;            // 10 tiles per row
constexpr int NTILES = TPR * TPR;       // 100
constexpr int KC = 44;                  // k-offsets per chunk
constexpr int NKC = NK / KC;            // 10 chunks
constexpr int SMOOTH_BLOCKS = NTILES * NKC;   // 1000
constexpr int HALO = 10;
constexpr int LW = TS + 2 * HALO;       // 52
constexpr int LSTRIDE = LW + 1;         // 53 (odd -> worst LDS conflict 2-way = free)

typedef float f32x4 __attribute__((ext_vector_type(4)));

__device__ __forceinline__ int clampi(int v, int lo, int hi) {
    return v < lo ? lo : (v > hi ? hi : v);
}

// full-block reduce; rbuf is 4 floats of shared mem. Safe to call twice
// (leading barrier protects rbuf reuse). Result valid on all threads.
__device__ __forceinline__ float block_reduce(float v, float* rbuf, int tid) {
    __syncthreads();
    for (int off = 32; off > 0; off >>= 1)
        v += __shfl_down(v, off, 64);
    if ((tid & 63) == 0) rbuf[tid >> 6] = v;
    __syncthreads();
    return rbuf[0] + rbuf[1] + rbuf[2] + rbuf[3];
}

// fixed-point: value * 2^32, accumulated in int64 (two's complement via u64).
// Integer atomics are associative -> deterministic across dispatch orders.
__device__ __forceinline__ unsigned long long to_fx(float v) {
    return (unsigned long long)(long long)((double)v * 4294967296.0);
}

// d_ws layout: [0]=acc_smooth u64, [1]=acc_data u64, [2] (offset 16)=counter u32
__global__ __launch_bounds__(256) void bsl_fused_kernel(
    const float* __restrict__ img,   // [H,W]
    const float* __restrict__ tgt,   // [H,W]
    const float* __restrict__ w,     // [440,H,W]
    unsigned long long* __restrict__ acc,   // 2 x u64
    unsigned int* __restrict__ counter,     // 1 x u32
    float* __restrict__ out)
{
    __shared__ float lds[LW * LSTRIDE];   // 52*53*4 = 11 KB
    __shared__ float rbuf[4];
    const int tid = threadIdx.x;

    const int tileId = blockIdx.x / NKC;
    const int kc     = blockIdx.x % NKC;
    const int ty = tileId / TPR, tx = tileId % TPR;
    const int y0 = ty * TS, x0 = tx * TS;

    // ---- stage img tile + halo into LDS (replicate padding via clamp) ----
    for (int e = tid; e < LW * LW; e += 256) {
        const int ly = e / LW, lx = e - ly * LW;
        const int gy = clampi(y0 - HALO + ly, 0, H_ - 1);
        const int gx = clampi(x0 - HALO + lx, 0, W_ - 1);
        lds[ly * LSTRIDE + lx] = img[gy * W_ + gx];
    }
    __syncthreads();

    // thread -> 4 consecutive pixels of the 32x32 tile
    const int row = tid >> 3;            // 0..31
    const int c4  = (tid & 7) * 4;       // 0,4,...,28
    const int cbase = (HALO + row) * LSTRIDE + HALO + c4;
    const float c0 = lds[cbase + 0];
    const float c1 = lds[cbase + 1];
    const float c2 = lds[cbase + 2];
    const float c3 = lds[cbase + 3];

    // ---- stream KC w-plane tiles (read-once -> nontemporal) ----
    float sacc = 0.f;
    const float* wp = w + (size_t)(kc * KC) * HW_ + (y0 + row) * W_ + x0 + c4;
#pragma unroll 4
    for (int kk = 0; kk < KC; ++kk) {
        const int bk  = kc * KC + kk;                 // w-plane index (center skipped)
        const int idx = (bk < 220) ? bk : bk + 1;     // re-insert center gap
        const int q   = idx / 21;
        const int di  = q - 10;
        const int dj  = idx - q * 21 - 10;

        const f32x4 w4 = __builtin_nontemporal_load((const f32x4*)wp);
        wp += HW_;

        const int nb = cbase + di * LSTRIDE + dj;     // wave-uniform offset add
        const float n0 = lds[nb + 0];
        const float n1 = lds[nb + 1];
        const float n2 = lds[nb + 2];
        const float n3 = lds[nb + 3];
        const float d0 = c0 - n0, d1 = c1 - n1, d2 = c2 - n2, d3 = c3 - n3;
        sacc += w4.x * d0 * d0;
        sacc += w4.y * d1 * d1;
        sacc += w4.z * d2 * d2;
        sacc += w4.w * d3 * d3;
    }

    const float ssum = block_reduce(sacc, rbuf, tid);

    // ---- data term: once per tile (kc==0 blocks) ----
    float dsum = 0.f;
    if (kc == 0) {
        const float4 t4 = *reinterpret_cast<const float4*>(
            tgt + (y0 + row) * W_ + x0 + c4);
        const float d0 = c0 - t4.x, d1 = c1 - t4.y;
        const float d2 = c2 - t4.z, d3 = c3 - t4.w;
        dsum = block_reduce(d0*d0 + d1*d1 + d2*d2 + d3*d3, rbuf, tid);
    }

    // ---- deterministic global accumulation + last-block finalize ----
    if (tid == 0) {
        atomicAdd(&acc[0], to_fx(ssum));
        if (kc == 0) atomicAdd(&acc[1], to_fx(dsum));
        __threadfence();
        const unsigned int old = atomicAdd(counter, 1u);
        if (old == (unsigned int)(SMOOTH_BLOCKS - 1)) {
            const long long a0 = (long long)atomicAdd(&acc[0], 0ull);
            const long long a1 = (long long)atomicAdd(&acc[1], 0ull);
            // H*W*LAM*mean(w d^2) = LAM * S / 440 ; data = D / (H*W)
            out[0] = (float)(128.0 * (double)a0 / (4294967296.0 * 440.0)
                             + (double)a1 / (4294967296.0 * 102400.0));
        }
    }
}

extern "C" void kernel_launch(void* const* d_in, const int* in_sizes, int n_in,
                              void* d_out, int out_size, void* d_ws, size_t ws_size,
                              hipStream_t stream) {
    const float* img = (const float*)d_in[0];   // output [320,320]
    const float* tgt = (const float*)d_in[1];   // target [320,320]
    const float* wij = (const float*)d_in[2];   // w_ij [440,320,320]
    float* out = (float*)d_out;
    unsigned long long* acc = (unsigned long long*)d_ws;
    unsigned int* counter = (unsigned int*)((char*)d_ws + 16);

    // re-zero accumulators + counter every call (d_ws is poisoned once, not
    // restored between replays; memset node is graph-capture-safe)
    hipMemsetAsync(d_ws, 0, 24, stream);
    bsl_fused_kernel<<<SMOOTH_BLOCKS, 256, 0, stream>>>(img, tgt, wij, acc, counter, out);
}

// Round 4
// 36.262 us; speedup vs baseline: 2.3227x; 2.3227x over previous
//
#include <hip/hip_runtime.h>
#include <cstddef>

// Problem constants (match reference)
constexpr int H_ = 320;
constexpr int W_ = 320;
constexpr int HW_ = H_ * W_;            // 102400
constexpr int NK = 440;                 // offsets excluding center
constexpr int TS = 32;                  // spatial tile edge
constexpr int TPR = W_ / TS;            // 10 tiles per row
constexpr int NTILES = TPR * TPR;       // 100
constexpr int KC = 20;                  // k-offsets per chunk
constexpr int NKC = NK / KC;            // 22 chunks
constexpr int SMOOTH_BLOCKS = NTILES * NKC;   // 2200
constexpr int NPART = SMOOTH_BLOCKS + NTILES; // 2300 partials
constexpr int HALO = 10;
constexpr int LW = TS + 2 * HALO;       // 52
constexpr int LSTRIDE = LW + 1;         // 53 (odd -> worst LDS conflict 2-way = free)

typedef float f32x4 __attribute__((ext_vector_type(4)));

__device__ __forceinline__ int clampi(int v, int lo, int hi) {
    return v < lo ? lo : (v > hi ? hi : v);
}

// full-block reduce; rbuf is 4 floats of shared mem. Safe to call twice
// (leading barrier protects rbuf reuse). Result valid on all threads.
__device__ __forceinline__ float block_reduce(float v, float* rbuf, int tid) {
    __syncthreads();
    for (int off = 32; off > 0; off >>= 1)
        v += __shfl_down(v, off, 64);
    if ((tid & 63) == 0) rbuf[tid >> 6] = v;
    __syncthreads();
    return rbuf[0] + rbuf[1] + rbuf[2] + rbuf[3];
}

__global__ __launch_bounds__(256) void bsl_main_kernel(
    const float* __restrict__ img,   // [H,W]
    const float* __restrict__ tgt,   // [H,W]
    const float* __restrict__ w,     // [440,H,W]
    float* __restrict__ partials)    // [NPART]
{
    __shared__ float lds[LW * LSTRIDE];   // 52*53*4 = 11 KB
    __shared__ float rbuf[4];
    const int tid = threadIdx.x;

    const int tileId = blockIdx.x / NKC;
    const int kc     = blockIdx.x % NKC;
    const int ty = tileId / TPR, tx = tileId % TPR;
    const int y0 = ty * TS, x0 = tx * TS;

    // ---- stage img tile + halo into LDS (replicate padding via clamp) ----
    for (int e = tid; e < LW * LW; e += 256) {
        const int ly = e / LW, lx = e - ly * LW;
        const int gy = clampi(y0 - HALO + ly, 0, H_ - 1);
        const int gx = clampi(x0 - HALO + lx, 0, W_ - 1);
        lds[ly * LSTRIDE + lx] = img[gy * W_ + gx];
    }
    __syncthreads();

    // thread -> 4 consecutive pixels of the 32x32 tile
    const int row = tid >> 3;            // 0..31
    const int c4  = (tid & 7) * 4;       // 0,4,...,28
    const int cbase = (HALO + row) * LSTRIDE + HALO + c4;
    const float c0 = lds[cbase + 0];
    const float c1 = lds[cbase + 1];
    const float c2 = lds[cbase + 2];
    const float c3 = lds[cbase + 3];

    // ---- stream KC w-plane tiles (read-once -> nontemporal) ----
    float sacc = 0.f;
    const float* wp = w + (size_t)(kc * KC) * HW_ + (y0 + row) * W_ + x0 + c4;
#pragma unroll 4
    for (int kk = 0; kk < KC; ++kk) {
        const int bk  = kc * KC + kk;                 // w-plane index (center skipped)
        const int idx = (bk < 220) ? bk : bk + 1;     // re-insert center gap
        const int q   = idx / 21;
        const int di  = q - 10;
        const int dj  = idx - q * 21 - 10;

        const f32x4 w4 = __builtin_nontemporal_load((const f32x4*)wp);
        wp += HW_;

        const int nb = cbase + di * LSTRIDE + dj;     // wave-uniform offset add
        const float n0 = lds[nb + 0];
        const float n1 = lds[nb + 1];
        const float n2 = lds[nb + 2];
        const float n3 = lds[nb + 3];
        const float d0 = c0 - n0, d1 = c1 - n1, d2 = c2 - n2, d3 = c3 - n3;
        sacc += w4.x * d0 * d0;
        sacc += w4.y * d1 * d1;
        sacc += w4.z * d2 * d2;
        sacc += w4.w * d3 * d3;
    }

    const float ssum = block_reduce(sacc, rbuf, tid);
    if (tid == 0) partials[blockIdx.x] = ssum;

    // ---- data term: once per tile (kc==0 blocks) ----
    if (kc == 0) {
        const float4 t4 = *reinterpret_cast<const float4*>(
            tgt + (y0 + row) * W_ + x0 + c4);
        const float d0 = c0 - t4.x, d1 = c1 - t4.y;
        const float d2 = c2 - t4.z, d3 = c3 - t4.w;
        const float dsum = block_reduce(d0*d0 + d1*d1 + d2*d2 + d3*d3, rbuf, tid);
        if (tid == 0) partials[SMOOTH_BLOCKS + tileId] = dsum;
    }
}

__global__ __launch_bounds__(256) void bsl_final_kernel(
    const float* __restrict__ partials, float* __restrict__ out)
{
    const int tid = threadIdx.x;
    double s = 0.0, d = 0.0;

    // smooth partials: 2200 floats = 2*1024 + 152 (152 % 4 == 0)
    for (int base = 0; base < SMOOTH_BLOCKS; base += 1024) {
        const int i = base + tid * 4;
        if (i + 4 <= SMOOTH_BLOCKS) {
            const float4 v = *reinterpret_cast<const float4*>(partials + i);
            s += (double)v.x + (double)v.y + (double)v.z + (double)v.w;
        }
    }
    // data partials: 100 floats
    if (tid < NTILES / 4) {
        const float4 v = *reinterpret_cast<const float4*>(
            partials + SMOOTH_BLOCKS + tid * 4);
        d += (double)v.x + (double)v.y + (double)v.z + (double)v.w;
    }

    __shared__ double sm[256];
    __shared__ double sd[256];
    sm[tid] = s; sd[tid] = d;
    __syncthreads();
    for (int st = 128; st > 0; st >>= 1) {
        if (tid < st) { sm[tid] += sm[tid + st]; sd[tid] += sd[tid + st]; }
        __syncthreads();
    }
    if (tid == 0) {
        // H*W*LAM*mean(w d^2) = LAM * S / 440 ; data = D / (H*W)
        out[0] = (float)(128.0 * sm[0] / 440.0 + sd[0] / (double)HW_);
    }
}

extern "C" void kernel_launch(void* const* d_in, const int* in_sizes, int n_in,
                              void* d_out, int out_size, void* d_ws, size_t ws_size,
                              hipStream_t stream) {
    const float* img = (const float*)d_in[0];   // output [320,320]
    const float* tgt = (const float*)d_in[1];   // target [320,320]
    const float* wij = (const float*)d_in[2];   // w_ij [440,320,320]
    float* out = (float*)d_out;
    float* partials = (float*)d_ws;             // NPART floats = 9.2 KB

    bsl_main_kernel<<<SMOOTH_BLOCKS, 256, 0, stream>>>(img, tgt, wij, partials);
    bsl_final_kernel<<<1, 256, 0, stream>>>(partials, out);
}